// Round 1
// baseline (7004.025 us; speedup 1.0000x reference)
//
#include <hip/hip_runtime.h>
#include <hip/hip_bf16.h>
#include <math.h>

// Model: 5x (conv1d + bias + LeakyReLU(0.1) + BatchNorm(train-stats)) on
// embedded context, then content attention over a 4096-slot memory, concat
// [emb(x), cfeat, m_out] -> fc -> softmax over 32000 vocab.
//
// Shapes: B*S = 1024 samples.
//  conv1: in [1024,64,256](gathered from emb via c) -> [1024,32,127]
//  conv2: -> [1024,64,62]   conv3: -> [1024,128,30]  conv4: -> [1024,256,14]
//  conv5: [1024,256*14=3584] x w5[512,3584]^T -> [1024,512]
//  scores = cfeat @ memK^T / sqrt(512) -> [1024,4096] -> softmax -> @memV
//  s [1024,1280] @ fcW [1280,32000] + fcb -> softmax -> d_out

#define N_SAMP 1024

// ---------------------------------------------------------------- reductions
__device__ __forceinline__ float blockReduceMax256(float v) {
    __shared__ float sm[4];
    #pragma unroll
    for (int off = 32; off > 0; off >>= 1) v = fmaxf(v, __shfl_down(v, off, 64));
    if ((threadIdx.x & 63) == 0) sm[threadIdx.x >> 6] = v;
    __syncthreads();
    v = fmaxf(fmaxf(sm[0], sm[1]), fmaxf(sm[2], sm[3]));
    __syncthreads();
    return v;
}

__device__ __forceinline__ float blockReduceSum256(float v) {
    __shared__ float sm[4];
    #pragma unroll
    for (int off = 32; off > 0; off >>= 1) v += __shfl_down(v, off, 64);
    if ((threadIdx.x & 63) == 0) sm[threadIdx.x >> 6] = v;
    __syncthreads();
    v = sm[0] + sm[1] + sm[2] + sm[3];
    __syncthreads();
    return v;
}

// ---------------------------------------------------------------- conv1
// y1[n,co,l] = leaky(b1[co] + sum_{ci<64,k<8} emb[c[n,ci]][2l-2+k] * w1[co,ci,k])
__global__ __launch_bounds__(128)
void conv1_kernel(const int* __restrict__ Cidx, const float* __restrict__ Emb,
                  const float* __restrict__ W, const float* __restrict__ Bias,
                  float* __restrict__ Y) {
    __shared__ float wls[64 * 8];
    __shared__ int idx[64];
    const int co = blockIdx.x;      // 32
    const int n  = blockIdx.y;      // 1024
    for (int i = threadIdx.x; i < 512; i += 128) wls[i] = W[co * 512 + i];
    if (threadIdx.x < 64) idx[threadIdx.x] = Cidx[n * 64 + threadIdx.x];
    __syncthreads();
    const int l = threadIdx.x;
    if (l >= 127) return;
    float acc = Bias[co];
    const int li0 = 2 * l - 2;
    for (int ci = 0; ci < 64; ci++) {
        const float* er = Emb + (size_t)idx[ci] * 256;
        const float* wr = wls + ci * 8;
        #pragma unroll
        for (int k = 0; k < 8; k++) {
            int li = li0 + k;
            if (li >= 0 && li < 256) acc = fmaf(er[li], wr[k], acc);
        }
    }
    acc = acc > 0.f ? acc : 0.1f * acc;
    Y[((size_t)n * 32 + co) * 127 + l] = acc;
}

// ---------------------------------------------------------------- generic conv
template<int CI, int KW, int STRIDE, int PAD, int LIN, int LOUT, int CO>
__global__ __launch_bounds__(256)
void conv_kernel(const float* __restrict__ X, const float* __restrict__ W,
                 const float* __restrict__ Bias, float* __restrict__ Y) {
    __shared__ float wls[CI * KW];
    const int co = blockIdx.x;
    for (int i = threadIdx.x; i < CI * KW; i += 256) wls[i] = W[(size_t)co * CI * KW + i];
    __syncthreads();
    const int o = blockIdx.y * 256 + threadIdx.x;  // grid sized so o < N*LOUT exactly
    const int n = o / LOUT, l = o % LOUT;
    const float* xr = X + (size_t)n * CI * LIN;
    float acc = Bias[co];
    const int li0 = l * STRIDE - PAD;
    for (int ci = 0; ci < CI; ci++) {
        const float* xc = xr + ci * LIN;
        const float* wr = wls + ci * KW;
        #pragma unroll
        for (int k = 0; k < KW; k++) {
            int li = li0 + k;
            if (li >= 0 && li < LIN) acc = fmaf(xc[li], wr[k], acc);
        }
    }
    acc = acc > 0.f ? acc : 0.1f * acc;
    Y[((size_t)n * CO + co) * LOUT + l] = acc;
}

// ---------------------------------------------------------------- batchnorm
// One block per channel: compute mean/var (double accum) over N*L, then
// normalize in place: y = y*scale + shift.
__global__ __launch_bounds__(256)
void bn_kernel(float* __restrict__ Y, const float* __restrict__ G,
               const float* __restrict__ Be, int C, int L, int N) {
    const int c = blockIdx.x;
    const int total = N * L;
    double s = 0.0, s2 = 0.0;
    for (int i = threadIdx.x; i < total; i += 256) {
        int n = i / L, l = i - n * L;
        float v = Y[((size_t)n * C + c) * L + l];
        s += v; s2 += (double)v * v;
    }
    __shared__ double r1[256], r2[256];
    r1[threadIdx.x] = s; r2[threadIdx.x] = s2;
    __syncthreads();
    for (int off = 128; off > 0; off >>= 1) {
        if (threadIdx.x < off) { r1[threadIdx.x] += r1[threadIdx.x + off];
                                 r2[threadIdx.x] += r2[threadIdx.x + off]; }
        __syncthreads();
    }
    __shared__ float sc, sh;
    if (threadIdx.x == 0) {
        double cnt = (double)total;
        double mu = r1[0] / cnt;
        double var = r2[0] / cnt - mu * mu;
        float scale = (float)((double)G[c] / sqrt(var + 1e-5));
        sc = scale;
        sh = (float)((double)Be[c] - mu * scale);
    }
    __syncthreads();
    const float scale = sc, shift = sh;
    for (int i = threadIdx.x; i < total; i += 256) {
        int n = i / L, l = i - n * L;
        size_t p = ((size_t)n * C + c) * L + l;
        Y[p] = fmaf(Y[p], scale, shift);
    }
}

// ---------------------------------------------------------------- GEMM
// C[m,n] = act(scale * sum_k A[m,k]*B[.,.] + bias[n]); B row-major [K,N] or,
// if TRANSB, row-major [N,K]. All dims divisible by tiles; 256 threads.
template<int BM, int BN, int KS, int TM, int TN, bool TRANSB>
__global__ __launch_bounds__(256)
void gemm_kernel(const float* __restrict__ A, const float* __restrict__ B,
                 const float* __restrict__ bias, float* __restrict__ C,
                 int M, int N, int K, float scale, int leaky) {
    constexpr int TX = BN / TN;
    constexpr int TY = BM / TM;
    static_assert(TX * TY == 256, "block mismatch");
    static_assert(BM * KS == 1024, "A tile = 1 float4/thread");
    __shared__ float As[KS][BM];
    __shared__ float Bs[KS][BN];
    const int tid = threadIdx.x;
    const int tx = tid % TX, ty = tid / TX;
    const int row0 = blockIdx.x * BM, col0 = blockIdx.y * BN;

    float acc[TM][TN] = {};

    constexpr int KQ = KS / 4;
    const int am = tid / KQ;
    const int ak = (tid % KQ) * 4;
    const float* Aptr = A + (size_t)(row0 + am) * K + ak;

    int bn_, bk_;
    const float* Bptr;
    if (TRANSB) {
        bn_ = tid / KQ; bk_ = (tid % KQ) * 4;
        Bptr = B + (size_t)(col0 + bn_) * K + bk_;
    } else {
        bk_ = (tid * 4) / BN; bn_ = (tid * 4) % BN;
        Bptr = B + (size_t)bk_ * N + col0 + bn_;
    }

    for (int k0 = 0; k0 < K; k0 += KS) {
        float4 av = *(const float4*)(Aptr + k0);
        float4 bv;
        if (TRANSB) bv = *(const float4*)(Bptr + k0);
        else        bv = *(const float4*)(Bptr + (size_t)k0 * N);
        __syncthreads();
        As[ak + 0][am] = av.x; As[ak + 1][am] = av.y;
        As[ak + 2][am] = av.z; As[ak + 3][am] = av.w;
        if (TRANSB) {
            Bs[bk_ + 0][bn_] = bv.x; Bs[bk_ + 1][bn_] = bv.y;
            Bs[bk_ + 2][bn_] = bv.z; Bs[bk_ + 3][bn_] = bv.w;
        } else {
            *(float4*)&Bs[bk_][bn_] = bv;
        }
        __syncthreads();
        #pragma unroll
        for (int kk = 0; kk < KS; kk++) {
            float a[TM], b[TN];
            #pragma unroll
            for (int i = 0; i < TM; i += 4)
                *(float4*)&a[i] = *(const float4*)&As[kk][ty * TM + i];
            #pragma unroll
            for (int j = 0; j < TN; j += 4)
                *(float4*)&b[j] = *(const float4*)&Bs[kk][tx * TN + j];
            #pragma unroll
            for (int i = 0; i < TM; i++)
                #pragma unroll
                for (int j = 0; j < TN; j++)
                    acc[i][j] = fmaf(a[i], b[j], acc[i][j]);
        }
    }

    #pragma unroll
    for (int i = 0; i < TM; i++) {
        const int m = row0 + ty * TM + i;
        #pragma unroll
        for (int j = 0; j < TN; j += 4) {
            const int n = col0 + tx * TN + j;
            float4 v;
            float* vp = (float*)&v;
            #pragma unroll
            for (int q = 0; q < 4; q++) {
                float t = acc[i][j + q] * scale + (bias ? bias[n + q] : 0.f);
                if (leaky) t = t > 0.f ? t : 0.1f * t;
                vp[q] = t;
            }
            *(float4*)&C[(size_t)m * N + n] = v;
        }
    }
}

// ---------------------------------------------------------------- softmax 4096 (regs)
__global__ __launch_bounds__(256)
void softmax4k_kernel(float* __restrict__ P) {
    float* p = P + (size_t)blockIdx.x * 4096;
    float v[16];
    float mx = -INFINITY;
    #pragma unroll
    for (int i = 0; i < 16; i++) {
        v[i] = p[threadIdx.x + i * 256];
        mx = fmaxf(mx, v[i]);
    }
    mx = blockReduceMax256(mx);
    float s = 0.f;
    #pragma unroll
    for (int i = 0; i < 16; i++) { v[i] = __expf(v[i] - mx); s += v[i]; }
    s = blockReduceSum256(s);
    const float inv = 1.f / s;
    #pragma unroll
    for (int i = 0; i < 16; i++) p[threadIdx.x + i * 256] = v[i] * inv;
}

// ---------------------------------------------------------------- softmax 32000 (3-pass)
__global__ __launch_bounds__(256)
void softmax_fc_kernel(float* __restrict__ P) {
    float* p = P + (size_t)blockIdx.x * 32000;
    float mx = -INFINITY;
    for (int i = threadIdx.x; i < 32000; i += 256) mx = fmaxf(mx, p[i]);
    mx = blockReduceMax256(mx);
    float s = 0.f;
    for (int i = threadIdx.x; i < 32000; i += 256) {
        float e = __expf(p[i] - mx);
        p[i] = e; s += e;
    }
    s = blockReduceSum256(s);
    const float inv = 1.f / s;
    for (int i = threadIdx.x; i < 32000; i += 256) p[i] *= inv;
}

// ---------------------------------------------------------------- assemble s
// s[m, 0:256]=emb[x[m]]; [256:768]=cfeat[m]; [768:1280]=m_out[m]
__global__ __launch_bounds__(320)
void assemble_s_kernel(const int* __restrict__ X, const float* __restrict__ Emb,
                       const float* __restrict__ Cf, const float* __restrict__ Mo,
                       float* __restrict__ S) {
    const int m = blockIdx.x;
    const int col = threadIdx.x * 4;
    float4 v;
    if (col < 256)      v = *(const float4*)(Emb + (size_t)X[m] * 256 + col);
    else if (col < 768) v = *(const float4*)(Cf + (size_t)m * 512 + (col - 256));
    else                v = *(const float4*)(Mo + (size_t)m * 512 + (col - 768));
    *(float4*)(S + (size_t)m * 1280 + col) = v;
}

// ---------------------------------------------------------------- launch
extern "C" void kernel_launch(void* const* d_in, const int* in_sizes, int n_in,
                              void* d_out, int out_size, void* d_ws, size_t ws_size,
                              hipStream_t stream) {
    const int*   x    = (const int*)d_in[0];
    const int*   c    = (const int*)d_in[1];
    const float* emb  = (const float*)d_in[2];
    const float* w1 = (const float*)d_in[3],  *b1 = (const float*)d_in[4];
    const float* g1 = (const float*)d_in[5],  *be1 = (const float*)d_in[6];
    const float* w2 = (const float*)d_in[7],  *b2 = (const float*)d_in[8];
    const float* g2 = (const float*)d_in[9],  *be2 = (const float*)d_in[10];
    const float* w3 = (const float*)d_in[11], *b3 = (const float*)d_in[12];
    const float* g3 = (const float*)d_in[13], *be3 = (const float*)d_in[14];
    const float* w4 = (const float*)d_in[15], *b4 = (const float*)d_in[16];
    const float* g4 = (const float*)d_in[17], *be4 = (const float*)d_in[18];
    const float* w5 = (const float*)d_in[19], *b5 = (const float*)d_in[20];
    const float* g5 = (const float*)d_in[21], *be5 = (const float*)d_in[22];
    const float* fcW = (const float*)d_in[23], *fcb = (const float*)d_in[24];
    const float* memK = (const float*)d_in[25], *memV = (const float*)d_in[26];
    float* out = (float*)d_out;

    float* ws = (float*)d_ws;
    // ws layout (floats), with aliasing: y3->y1's slot, y4->y2's slot
    float* y1     = ws;                       // 1024*32*127 = 4,161,536
    float* y2     = ws + 4161536;             // 1024*64*62  = 3,964,928
    float* y3     = y1;                       // 1024*128*30 = 3,932,160
    float* y4     = y2;                       // 1024*256*14 = 3,670,016
    float* cfeat  = ws + 8126464;             // 1024*512
    float* scores = ws + 8650752;             // 1024*4096
    float* m_out  = ws + 12845056;            // 1024*512
    float* s      = ws + 13369344;            // 1024*1280  (ends 14,680,064 = 58.7MB)

    // conv stack
    conv1_kernel<<<dim3(32, N_SAMP), 128, 0, stream>>>(c, emb, w1, b1, y1);
    bn_kernel<<<32, 256, 0, stream>>>(y1, g1, be1, 32, 127, N_SAMP);
    conv_kernel<32, 8, 2, 2, 127, 62, 64><<<dim3(64, 248), 256, 0, stream>>>(y1, w2, b2, y2);
    bn_kernel<<<64, 256, 0, stream>>>(y2, g2, be2, 64, 62, N_SAMP);
    conv_kernel<64, 8, 2, 2, 62, 30, 128><<<dim3(128, 120), 256, 0, stream>>>(y2, w3, b3, y3);
    bn_kernel<<<128, 256, 0, stream>>>(y3, g3, be3, 128, 30, N_SAMP);
    conv_kernel<128, 8, 2, 2, 30, 14, 256><<<dim3(256, 56), 256, 0, stream>>>(y3, w4, b4, y4);
    bn_kernel<<<256, 256, 0, stream>>>(y4, g4, be4, 256, 14, N_SAMP);
    // conv5 as GEMM: [1024,3584] x w5[512,3584]^T + b5, leaky
    gemm_kernel<64, 64, 16, 4, 4, true><<<dim3(16, 8), 256, 0, stream>>>(
        y4, w5, b5, cfeat, 1024, 512, 3584, 1.0f, 1);
    bn_kernel<<<512, 256, 0, stream>>>(cfeat, g5, be5, 512, 1, N_SAMP);

    // attention over memory
    gemm_kernel<64, 64, 16, 4, 4, true><<<dim3(16, 64), 256, 0, stream>>>(
        cfeat, memK, nullptr, scores, 1024, 4096, 512, 0.04419417382415922f, 0);
    softmax4k_kernel<<<1024, 256, 0, stream>>>(scores);
    gemm_kernel<64, 64, 16, 4, 4, false><<<dim3(16, 8), 256, 0, stream>>>(
        scores, memV, nullptr, m_out, 1024, 512, 4096, 1.0f, 0);

    // concat + fc + softmax
    assemble_s_kernel<<<1024, 320, 0, stream>>>(x, emb, cfeat, m_out, s);
    gemm_kernel<128, 128, 8, 8, 8, false><<<dim3(8, 250), 256, 0, stream>>>(
        s, fcW, fcb, out, 1024, 32000, 1280, 1.0f, 0);
    softmax_fc_kernel<<<1024, 256, 0, stream>>>(out);
}

// Round 2
// 2991.161 us; speedup vs baseline: 2.3416x; 2.3416x over previous
//
#include <hip/hip_runtime.h>
#include <hip/hip_bf16.h>
#include <math.h>

// Model: 5x (conv1d + bias + LeakyReLU(0.1) + BatchNorm(train-stats)) on
// embedded context, then content attention over a 4096-slot memory, concat
// [emb(x), cfeat, m_out] -> fc -> softmax over 32000 vocab.
//
// Shapes: B*S = 1024 samples.
//  conv1: in [1024,64,256](gathered from emb via c) -> [1024,32,127]
//  conv2: -> [1024,64,62]   conv3: -> [1024,128,30]  conv4: -> [1024,256,14]
//  conv5: [1024,256*14=3584] x w5[512,3584]^T -> [1024,512]
//  scores = cfeat @ memK^T / sqrt(512) -> [1024,4096] -> softmax -> @memV
//  s [1024,1280] @ fcW [1280,32000] + fcb -> softmax -> d_out

#define N_SAMP 1024

// ---------------------------------------------------------------- reductions
__device__ __forceinline__ float blockReduceMax256(float v) {
    __shared__ float sm[4];
    #pragma unroll
    for (int off = 32; off > 0; off >>= 1) v = fmaxf(v, __shfl_down(v, off, 64));
    if ((threadIdx.x & 63) == 0) sm[threadIdx.x >> 6] = v;
    __syncthreads();
    v = fmaxf(fmaxf(sm[0], sm[1]), fmaxf(sm[2], sm[3]));
    __syncthreads();
    return v;
}

__device__ __forceinline__ float blockReduceSum256(float v) {
    __shared__ float sm[4];
    #pragma unroll
    for (int off = 32; off > 0; off >>= 1) v += __shfl_down(v, off, 64);
    if ((threadIdx.x & 63) == 0) sm[threadIdx.x >> 6] = v;
    __syncthreads();
    v = sm[0] + sm[1] + sm[2] + sm[3];
    __syncthreads();
    return v;
}

// ---------------------------------------------------------------- unified conv
// One block = (one sample n, one group of COG output channels).
// Loops over ci in chunks of CICH: stages the X chunk (zero-padded rows, no
// bounds checks in hot loop) and the W chunk in LDS, then register-blocked
// accumulation: each thread owns (co, LB output positions).
// Lane map: co fastest -> x-reads are wave-broadcast; W rows padded to odd
// stride -> w-reads conflict-free.
template<int CI, int KW, int STRIDE, int PAD, int LIN, int LOUT, int CO,
         int COG, int LB, int CICH, bool GATHER>
__global__ __launch_bounds__(256)
void conv_lds_kernel(const float* __restrict__ Xg, const int* __restrict__ Cidx,
                     const float* __restrict__ Emb,
                     const float* __restrict__ W, const float* __restrict__ Bias,
                     float* __restrict__ Y) {
    constexpr int CHUNKS = 256 / COG;
    static_assert(COG * CHUNKS == 256, "bad block");
    constexpr int LOUT_PAD = CHUNKS * LB;
    static_assert(LOUT_PAD >= LOUT, "LB too small");
    constexpr int XR = LOUT_PAD * STRIDE + KW;     // padded LDS row length
    constexpr int WROW = CICH * KW + 1;            // odd padded W row
    static_assert(CI % CICH == 0, "ci chunking");

    __shared__ float Xs[CICH * XR];
    __shared__ float Ws[COG * WROW];
    __shared__ int idx[GATHER ? CI : 1];

    const int n   = blockIdx.y;
    const int co0 = blockIdx.x * COG;
    const int tid = threadIdx.x;
    const int co    = tid % COG;    // fastest within wave
    const int chunk = tid / COG;
    const int l0 = chunk * LB;

    if constexpr (GATHER) {
        if (tid < CI) idx[tid] = Cidx[n * CI + tid];
        __syncthreads();
    }

    float acc[LB];
    #pragma unroll
    for (int l = 0; l < LB; l++) acc[l] = 0.f;

    for (int c0 = 0; c0 < CI; c0 += CICH) {
        // stage X chunk (zero-padded)
        for (int i = tid; i < CICH * XR; i += 256) {
            const int ci_l = i / XR;
            const int j = i - ci_l * XR;
            const int li = j - PAD;
            float v = 0.f;
            if (li >= 0 && li < LIN) {
                if constexpr (GATHER)
                    v = Emb[(size_t)idx[c0 + ci_l] * 256 + li];
                else
                    v = Xg[((size_t)n * CI + c0 + ci_l) * LIN + li];
            }
            Xs[i] = v;
        }
        // stage W chunk
        for (int i = tid; i < COG * (CICH * KW); i += 256) {
            const int cw = i / (CICH * KW);
            const int r  = i - cw * (CICH * KW);
            Ws[cw * WROW + r] = W[((size_t)(co0 + cw) * CI + c0) * KW + r];
        }
        __syncthreads();

        #pragma unroll 2
        for (int ci_l = 0; ci_l < CICH; ci_l++) {
            float wv[KW];
            #pragma unroll
            for (int k = 0; k < KW; k++) wv[k] = Ws[co * WROW + ci_l * KW + k];
            constexpr int XW = (LB - 1) * STRIDE + KW;
            float xv[XW];
            #pragma unroll
            for (int j = 0; j < XW; j++) xv[j] = Xs[ci_l * XR + l0 * STRIDE + j];
            #pragma unroll
            for (int l = 0; l < LB; l++)
                #pragma unroll
                for (int k = 0; k < KW; k++)
                    acc[l] = fmaf(xv[l * STRIDE + k], wv[k], acc[l]);
        }
        __syncthreads();
    }

    const float b = Bias[co0 + co];
    float* yr = Y + ((size_t)n * CO + co0 + co) * LOUT;
    #pragma unroll
    for (int l = 0; l < LB; l++) {
        const int ll = l0 + l;
        if (ll < LOUT) {
            float t = acc[l] + b;
            yr[ll] = t > 0.f ? t : 0.1f * t;
        }
    }
}

// ---------------------------------------------------------------- batchnorm
__global__ __launch_bounds__(256)
void bn_kernel(float* __restrict__ Y, const float* __restrict__ G,
               const float* __restrict__ Be, int C, int L, int N) {
    const int c = blockIdx.x;
    const int total = N * L;
    double s = 0.0, s2 = 0.0;
    for (int i = threadIdx.x; i < total; i += 256) {
        int n = i / L, l = i - n * L;
        float v = Y[((size_t)n * C + c) * L + l];
        s += v; s2 += (double)v * v;
    }
    __shared__ double r1[256], r2[256];
    r1[threadIdx.x] = s; r2[threadIdx.x] = s2;
    __syncthreads();
    for (int off = 128; off > 0; off >>= 1) {
        if (threadIdx.x < off) { r1[threadIdx.x] += r1[threadIdx.x + off];
                                 r2[threadIdx.x] += r2[threadIdx.x + off]; }
        __syncthreads();
    }
    __shared__ float sc, sh;
    if (threadIdx.x == 0) {
        double cnt = (double)total;
        double mu = r1[0] / cnt;
        double var = r2[0] / cnt - mu * mu;
        float scale = (float)((double)G[c] / sqrt(var + 1e-5));
        sc = scale;
        sh = (float)((double)Be[c] - mu * scale);
    }
    __syncthreads();
    const float scale = sc, shift = sh;
    for (int i = threadIdx.x; i < total; i += 256) {
        int n = i / L, l = i - n * L;
        size_t p = ((size_t)n * C + c) * L + l;
        Y[p] = fmaf(Y[p], scale, shift);
    }
}

// ---------------------------------------------------------------- GEMM
template<int BM, int BN, int KS, int TM, int TN, bool TRANSB>
__global__ __launch_bounds__(256)
void gemm_kernel(const float* __restrict__ A, const float* __restrict__ B,
                 const float* __restrict__ bias, float* __restrict__ C,
                 int M, int N, int K, float scale, int leaky) {
    constexpr int TX = BN / TN;
    constexpr int TY = BM / TM;
    static_assert(TX * TY == 256, "block mismatch");
    static_assert(BM * KS == 1024, "A tile = 1 float4/thread");
    __shared__ float As[KS][BM];
    __shared__ float Bs[KS][BN];
    const int tid = threadIdx.x;
    const int tx = tid % TX, ty = tid / TX;
    const int row0 = blockIdx.x * BM, col0 = blockIdx.y * BN;

    float acc[TM][TN] = {};

    constexpr int KQ = KS / 4;
    const int am = tid / KQ;
    const int ak = (tid % KQ) * 4;
    const float* Aptr = A + (size_t)(row0 + am) * K + ak;

    int bn_, bk_;
    const float* Bptr;
    if (TRANSB) {
        bn_ = tid / KQ; bk_ = (tid % KQ) * 4;
        Bptr = B + (size_t)(col0 + bn_) * K + bk_;
    } else {
        bk_ = (tid * 4) / BN; bn_ = (tid * 4) % BN;
        Bptr = B + (size_t)bk_ * N + col0 + bn_;
    }

    for (int k0 = 0; k0 < K; k0 += KS) {
        float4 av = *(const float4*)(Aptr + k0);
        float4 bv;
        if (TRANSB) bv = *(const float4*)(Bptr + k0);
        else        bv = *(const float4*)(Bptr + (size_t)k0 * N);
        __syncthreads();
        As[ak + 0][am] = av.x; As[ak + 1][am] = av.y;
        As[ak + 2][am] = av.z; As[ak + 3][am] = av.w;
        if (TRANSB) {
            Bs[bk_ + 0][bn_] = bv.x; Bs[bk_ + 1][bn_] = bv.y;
            Bs[bk_ + 2][bn_] = bv.z; Bs[bk_ + 3][bn_] = bv.w;
        } else {
            *(float4*)&Bs[bk_][bn_] = bv;
        }
        __syncthreads();
        #pragma unroll
        for (int kk = 0; kk < KS; kk++) {
            float a[TM], b[TN];
            #pragma unroll
            for (int i = 0; i < TM; i += 4)
                *(float4*)&a[i] = *(const float4*)&As[kk][ty * TM + i];
            #pragma unroll
            for (int j = 0; j < TN; j += 4)
                *(float4*)&b[j] = *(const float4*)&Bs[kk][tx * TN + j];
            #pragma unroll
            for (int i = 0; i < TM; i++)
                #pragma unroll
                for (int j = 0; j < TN; j++)
                    acc[i][j] = fmaf(a[i], b[j], acc[i][j]);
        }
    }

    #pragma unroll
    for (int i = 0; i < TM; i++) {
        const int m = row0 + ty * TM + i;
        #pragma unroll
        for (int j = 0; j < TN; j += 4) {
            const int n = col0 + tx * TN + j;
            float4 v;
            float* vp = (float*)&v;
            #pragma unroll
            for (int q = 0; q < 4; q++) {
                float t = acc[i][j + q] * scale + (bias ? bias[n + q] : 0.f);
                if (leaky) t = t > 0.f ? t : 0.1f * t;
                vp[q] = t;
            }
            *(float4*)&C[(size_t)m * N + n] = v;
        }
    }
}

// ---------------------------------------------------------------- softmax 4096 (regs)
__global__ __launch_bounds__(256)
void softmax4k_kernel(float* __restrict__ P) {
    float* p = P + (size_t)blockIdx.x * 4096;
    float v[16];
    float mx = -INFINITY;
    #pragma unroll
    for (int i = 0; i < 16; i++) {
        v[i] = p[threadIdx.x + i * 256];
        mx = fmaxf(mx, v[i]);
    }
    mx = blockReduceMax256(mx);
    float s = 0.f;
    #pragma unroll
    for (int i = 0; i < 16; i++) { v[i] = __expf(v[i] - mx); s += v[i]; }
    s = blockReduceSum256(s);
    const float inv = 1.f / s;
    #pragma unroll
    for (int i = 0; i < 16; i++) p[threadIdx.x + i * 256] = v[i] * inv;
}

// ---------------------------------------------------------------- softmax 32000 (3-pass)
__global__ __launch_bounds__(256)
void softmax_fc_kernel(float* __restrict__ P) {
    float* p = P + (size_t)blockIdx.x * 32000;
    float mx = -INFINITY;
    for (int i = threadIdx.x; i < 32000; i += 256) mx = fmaxf(mx, p[i]);
    mx = blockReduceMax256(mx);
    float s = 0.f;
    for (int i = threadIdx.x; i < 32000; i += 256) {
        float e = __expf(p[i] - mx);
        p[i] = e; s += e;
    }
    s = blockReduceSum256(s);
    const float inv = 1.f / s;
    for (int i = threadIdx.x; i < 32000; i += 256) p[i] *= inv;
}

// ---------------------------------------------------------------- assemble s
__global__ __launch_bounds__(320)
void assemble_s_kernel(const int* __restrict__ X, const float* __restrict__ Emb,
                       const float* __restrict__ Cf, const float* __restrict__ Mo,
                       float* __restrict__ S) {
    const int m = blockIdx.x;
    const int col = threadIdx.x * 4;
    float4 v;
    if (col < 256)      v = *(const float4*)(Emb + (size_t)X[m] * 256 + col);
    else if (col < 768) v = *(const float4*)(Cf + (size_t)m * 512 + (col - 256));
    else                v = *(const float4*)(Mo + (size_t)m * 512 + (col - 768));
    *(float4*)(S + (size_t)m * 1280 + col) = v;
}

// ---------------------------------------------------------------- launch
extern "C" void kernel_launch(void* const* d_in, const int* in_sizes, int n_in,
                              void* d_out, int out_size, void* d_ws, size_t ws_size,
                              hipStream_t stream) {
    const int*   x    = (const int*)d_in[0];
    const int*   c    = (const int*)d_in[1];
    const float* emb  = (const float*)d_in[2];
    const float* w1 = (const float*)d_in[3],  *b1 = (const float*)d_in[4];
    const float* g1 = (const float*)d_in[5],  *be1 = (const float*)d_in[6];
    const float* w2 = (const float*)d_in[7],  *b2 = (const float*)d_in[8];
    const float* g2 = (const float*)d_in[9],  *be2 = (const float*)d_in[10];
    const float* w3 = (const float*)d_in[11], *b3 = (const float*)d_in[12];
    const float* g3 = (const float*)d_in[13], *be3 = (const float*)d_in[14];
    const float* w4 = (const float*)d_in[15], *b4 = (const float*)d_in[16];
    const float* g4 = (const float*)d_in[17], *be4 = (const float*)d_in[18];
    const float* w5 = (const float*)d_in[19], *b5 = (const float*)d_in[20];
    const float* g5 = (const float*)d_in[21], *be5 = (const float*)d_in[22];
    const float* fcW = (const float*)d_in[23], *fcb = (const float*)d_in[24];
    const float* memK = (const float*)d_in[25], *memV = (const float*)d_in[26];
    float* out = (float*)d_out;

    float* ws = (float*)d_ws;
    float* y1     = ws;                       // 1024*32*127 = 4,161,536
    float* y2     = ws + 4161536;             // 1024*64*62  = 3,964,928
    float* y3     = y1;                       // 1024*128*30 = 3,932,160
    float* y4     = y2;                       // 1024*256*14 = 3,670,016
    float* cfeat  = ws + 8126464;             // 1024*512
    float* scores = ws + 8650752;             // 1024*4096
    float* m_out  = ws + 12845056;            // 1024*512
    float* s      = ws + 13369344;            // 1024*1280

    // conv stack (unified LDS conv kernels)
    // conv1: CI=64(ctx pos via gather), LIN=256, LOUT=127, CO=32
    conv_lds_kernel<64, 8, 2, 2, 256, 127, 32, 32, 16, 16, true>
        <<<dim3(1, N_SAMP), 256, 0, stream>>>(nullptr, c, emb, w1, b1, y1);
    bn_kernel<<<32, 256, 0, stream>>>(y1, g1, be1, 32, 127, N_SAMP);
    conv_lds_kernel<32, 8, 2, 2, 127, 62, 64, 32, 8, 16, false>
        <<<dim3(2, N_SAMP), 256, 0, stream>>>(y1, nullptr, nullptr, w2, b2, y2);
    bn_kernel<<<64, 256, 0, stream>>>(y2, g2, be2, 64, 62, N_SAMP);
    conv_lds_kernel<64, 8, 2, 2, 62, 30, 128, 64, 8, 16, false>
        <<<dim3(2, N_SAMP), 256, 0, stream>>>(y2, nullptr, nullptr, w3, b3, y3);
    bn_kernel<<<128, 256, 0, stream>>>(y3, g3, be3, 128, 30, N_SAMP);
    conv_lds_kernel<128, 8, 2, 2, 30, 14, 256, 128, 8, 8, false>
        <<<dim3(2, N_SAMP), 256, 0, stream>>>(y3, nullptr, nullptr, w4, b4, y4);
    bn_kernel<<<256, 256, 0, stream>>>(y4, g4, be4, 256, 14, N_SAMP);
    // conv5 as GEMM: [1024,3584] x w5[512,3584]^T + b5, leaky
    gemm_kernel<64, 64, 16, 4, 4, true><<<dim3(16, 8), 256, 0, stream>>>(
        y4, w5, b5, cfeat, 1024, 512, 3584, 1.0f, 1);
    bn_kernel<<<512, 256, 0, stream>>>(cfeat, g5, be5, 512, 1, N_SAMP);

    // attention over memory
    gemm_kernel<64, 64, 16, 4, 4, true><<<dim3(16, 64), 256, 0, stream>>>(
        cfeat, memK, nullptr, scores, 1024, 4096, 512, 0.04419417382415922f, 0);
    softmax4k_kernel<<<1024, 256, 0, stream>>>(scores);
    gemm_kernel<64, 64, 16, 4, 4, false><<<dim3(16, 8), 256, 0, stream>>>(
        scores, memV, nullptr, m_out, 1024, 512, 4096, 1.0f, 0);

    // concat + fc + softmax
    assemble_s_kernel<<<1024, 320, 0, stream>>>(x, emb, cfeat, m_out, s);
    gemm_kernel<128, 128, 8, 8, 8, false><<<dim3(8, 250), 256, 0, stream>>>(
        s, fcW, fcb, out, 1024, 32000, 1280, 1.0f, 0);
    softmax_fc_kernel<<<1024, 256, 0, stream>>>(out);
}

// Round 3
// 1925.502 us; speedup vs baseline: 3.6375x; 1.5534x over previous
//
#include <hip/hip_runtime.h>
#include <hip/hip_bf16.h>
#include <math.h>

// Model: 5x (conv1d + bias + LeakyReLU(0.1) + BatchNorm(train-stats)) on
// embedded context, then content attention over a 4096-slot memory, concat
// [emb(x), cfeat, m_out] -> fc -> softmax over 32000 vocab.
// All GEMM-shaped compute in bf16 MFMA (16x16x32), fp32 accumulate.

#define N_SAMP 1024

typedef __bf16 bf16x8 __attribute__((ext_vector_type(8)));
typedef __bf16 bf16x4 __attribute__((ext_vector_type(4)));
typedef float  f32x4  __attribute__((ext_vector_type(4)));

// ---------------------------------------------------------------- reductions
__device__ __forceinline__ float blockReduceMax256(float v) {
    __shared__ float sm[4];
    #pragma unroll
    for (int off = 32; off > 0; off >>= 1) v = fmaxf(v, __shfl_down(v, off, 64));
    if ((threadIdx.x & 63) == 0) sm[threadIdx.x >> 6] = v;
    __syncthreads();
    v = fmaxf(fmaxf(sm[0], sm[1]), fmaxf(sm[2], sm[3]));
    __syncthreads();
    return v;
}

__device__ __forceinline__ float blockReduceSum256(float v) {
    __shared__ float sm[4];
    #pragma unroll
    for (int off = 32; off > 0; off >>= 1) v += __shfl_down(v, off, 64);
    if ((threadIdx.x & 63) == 0) sm[threadIdx.x >> 6] = v;
    __syncthreads();
    v = sm[0] + sm[1] + sm[2] + sm[3];
    __syncthreads();
    return v;
}

// ---------------------------------------------------------------- unified conv
template<int CI, int KW, int STRIDE, int PAD, int LIN, int LOUT, int CO,
         int COG, int LB, int CICH, bool GATHER>
__global__ __launch_bounds__(256)
void conv_lds_kernel(const float* __restrict__ Xg, const int* __restrict__ Cidx,
                     const float* __restrict__ Emb,
                     const float* __restrict__ W, const float* __restrict__ Bias,
                     float* __restrict__ Y) {
    constexpr int CHUNKS = 256 / COG;
    static_assert(COG * CHUNKS == 256, "bad block");
    constexpr int LOUT_PAD = CHUNKS * LB;
    static_assert(LOUT_PAD >= LOUT, "LB too small");
    constexpr int XR = LOUT_PAD * STRIDE + KW;
    constexpr int WROW = CICH * KW + 1;
    static_assert(CI % CICH == 0, "ci chunking");

    __shared__ float Xs[CICH * XR];
    __shared__ float Ws[COG * WROW];
    __shared__ int idx[GATHER ? CI : 1];

    const int n   = blockIdx.y;
    const int co0 = blockIdx.x * COG;
    const int tid = threadIdx.x;
    const int co    = tid % COG;
    const int chunk = tid / COG;
    const int l0 = chunk * LB;

    if constexpr (GATHER) {
        if (tid < CI) idx[tid] = Cidx[n * CI + tid];
        __syncthreads();
    }

    float acc[LB];
    #pragma unroll
    for (int l = 0; l < LB; l++) acc[l] = 0.f;

    for (int c0 = 0; c0 < CI; c0 += CICH) {
        for (int i = tid; i < CICH * XR; i += 256) {
            const int ci_l = i / XR;
            const int j = i - ci_l * XR;
            const int li = j - PAD;
            float v = 0.f;
            if (li >= 0 && li < LIN) {
                if constexpr (GATHER)
                    v = Emb[(size_t)idx[c0 + ci_l] * 256 + li];
                else
                    v = Xg[((size_t)n * CI + c0 + ci_l) * LIN + li];
            }
            Xs[i] = v;
        }
        for (int i = tid; i < COG * (CICH * KW); i += 256) {
            const int cw = i / (CICH * KW);
            const int r  = i - cw * (CICH * KW);
            Ws[cw * WROW + r] = W[((size_t)(co0 + cw) * CI + c0) * KW + r];
        }
        __syncthreads();

        #pragma unroll 2
        for (int ci_l = 0; ci_l < CICH; ci_l++) {
            float wv[KW];
            #pragma unroll
            for (int k = 0; k < KW; k++) wv[k] = Ws[co * WROW + ci_l * KW + k];
            constexpr int XW = (LB - 1) * STRIDE + KW;
            float xv[XW];
            #pragma unroll
            for (int j = 0; j < XW; j++) xv[j] = Xs[ci_l * XR + l0 * STRIDE + j];
            #pragma unroll
            for (int l = 0; l < LB; l++)
                #pragma unroll
                for (int k = 0; k < KW; k++)
                    acc[l] = fmaf(xv[l * STRIDE + k], wv[k], acc[l]);
        }
        __syncthreads();
    }

    const float b = Bias[co0 + co];
    float* yr = Y + ((size_t)n * CO + co0 + co) * LOUT;
    #pragma unroll
    for (int l = 0; l < LB; l++) {
        const int ll = l0 + l;
        if (ll < LOUT) {
            float t = acc[l] + b;
            yr[ll] = t > 0.f ? t : 0.1f * t;
        }
    }
}

// ---------------------------------------------------------------- batchnorm
__global__ __launch_bounds__(256)
void bn_kernel(float* __restrict__ Y, const float* __restrict__ G,
               const float* __restrict__ Be, int C, int L, int N) {
    const int c = blockIdx.x;
    const int total = N * L;
    double s = 0.0, s2 = 0.0;
    for (int i = threadIdx.x; i < total; i += 256) {
        int n = i / L, l = i - n * L;
        float v = Y[((size_t)n * C + c) * L + l];
        s += v; s2 += (double)v * v;
    }
    __shared__ double r1[256], r2[256];
    r1[threadIdx.x] = s; r2[threadIdx.x] = s2;
    __syncthreads();
    for (int off = 128; off > 0; off >>= 1) {
        if (threadIdx.x < off) { r1[threadIdx.x] += r1[threadIdx.x + off];
                                 r2[threadIdx.x] += r2[threadIdx.x + off]; }
        __syncthreads();
    }
    __shared__ float sc, sh;
    if (threadIdx.x == 0) {
        double cnt = (double)total;
        double mu = r1[0] / cnt;
        double var = r2[0] / cnt - mu * mu;
        float scale = (float)((double)G[c] / sqrt(var + 1e-5));
        sc = scale;
        sh = (float)((double)Be[c] - mu * scale);
    }
    __syncthreads();
    const float scale = sc, shift = sh;
    for (int i = threadIdx.x; i < total; i += 256) {
        int n = i / L, l = i - n * L;
        size_t p = ((size_t)n * C + c) * L + l;
        Y[p] = fmaf(Y[p], scale, shift);
    }
}

// ---------------------------------------------------------------- MFMA GEMM
// C[M,N] f32 = act(scale * A[M,K]bf16 · B[N,K]bf16^T + bias[n]).
// Both operands K-major. 128x128 tile, BK=32, 4 waves in 2x2, each wave 64x64
// as 4x4 grid of 16x16x32 MFMAs. Staging via global_load_lds width=16.
__device__ __forceinline__ void gld16(const __bf16* g, __bf16* l) {
    __builtin_amdgcn_global_load_lds(
        (const __attribute__((address_space(1))) unsigned int*)g,
        (__attribute__((address_space(3))) unsigned int*)l, 16, 0, 0);
}

__global__ __launch_bounds__(256)
void mfma_gemm_bt(const __bf16* __restrict__ A, const __bf16* __restrict__ B,
                  const float* __restrict__ bias, float* __restrict__ C,
                  int M, int N, int K, float scale, int leaky) {
    __shared__ __bf16 As[128 * 32];
    __shared__ __bf16 Bs[128 * 32];
    const int tid = threadIdx.x;
    const int row0 = blockIdx.x * 128;
    const int col0 = blockIdx.y * 128;

    // staging: thread t loads 16B; LDS elem offset t*8 (+2048 for second half)
    // -> row t/4 (+64), k-elems (t%4)*8. Wave-uniform base + lane*16. ✓
    const int r  = tid >> 2;
    const int kb = (tid & 3) * 8;
    const __bf16* Ag0 = A + (size_t)(row0 + r) * K + kb;
    const __bf16* Ag1 = A + (size_t)(row0 + r + 64) * K + kb;
    const __bf16* Bg0 = B + (size_t)(col0 + r) * K + kb;
    const __bf16* Bg1 = B + (size_t)(col0 + r + 64) * K + kb;
    __bf16* Al0 = As + tid * 8;
    __bf16* Al1 = As + 2048 + tid * 8;
    __bf16* Bl0 = Bs + tid * 8;
    __bf16* Bl1 = Bs + 2048 + tid * 8;

    const int lane = tid & 63;
    const int wave = tid >> 6;
    const int wy = wave >> 1, wx = wave & 1;
    const int l15 = lane & 15, quad = lane >> 4;

    f32x4 acc[4][4] = {};

    for (int k0 = 0; k0 < K; k0 += 32) {
        __syncthreads();                 // all waves done reading prev tile
        gld16(Ag0 + k0, Al0);
        gld16(Ag1 + k0, Al1);
        gld16(Bg0 + k0, Bl0);
        gld16(Bg1 + k0, Bl1);
        __syncthreads();                 // drains vmcnt -> tiles resident

        bf16x8 af[4], bfr[4];
        #pragma unroll
        for (int mi = 0; mi < 4; mi++)
            af[mi] = *(const bf16x8*)&As[(wy * 64 + mi * 16 + l15) * 32 + quad * 8];
        #pragma unroll
        for (int ni = 0; ni < 4; ni++)
            bfr[ni] = *(const bf16x8*)&Bs[(wx * 64 + ni * 16 + l15) * 32 + quad * 8];
        #pragma unroll
        for (int mi = 0; mi < 4; mi++)
            #pragma unroll
            for (int ni = 0; ni < 4; ni++)
                acc[mi][ni] = __builtin_amdgcn_mfma_f32_16x16x32_bf16(
                    af[mi], bfr[ni], acc[mi][ni], 0, 0, 0);
    }

    // C/D layout: col = lane&15, row = quad*4 + reg
    #pragma unroll
    for (int mi = 0; mi < 4; mi++) {
        #pragma unroll
        for (int ni = 0; ni < 4; ni++) {
            const int col = col0 + wx * 64 + ni * 16 + l15;
            const float bv = bias ? bias[col] : 0.f;
            #pragma unroll
            for (int rg = 0; rg < 4; rg++) {
                const int row = row0 + wy * 64 + mi * 16 + quad * 4 + rg;
                float t = acc[mi][ni][rg] * scale + bv;
                if (leaky) t = t > 0.f ? t : 0.1f * t;
                C[(size_t)row * N + col] = t;
            }
        }
    }
}

// ---------------------------------------------------------------- casts
__global__ __launch_bounds__(256)
void cast_bf16_kernel(const float* __restrict__ in, __bf16* __restrict__ out, int n8) {
    int i = blockIdx.x * 256 + threadIdx.x;
    if (i >= n8) return;
    float4 a = ((const float4*)in)[2 * i];
    float4 b = ((const float4*)in)[2 * i + 1];
    bf16x8 v;
    v[0] = (__bf16)a.x; v[1] = (__bf16)a.y; v[2] = (__bf16)a.z; v[3] = (__bf16)a.w;
    v[4] = (__bf16)b.x; v[5] = (__bf16)b.y; v[6] = (__bf16)b.z; v[7] = (__bf16)b.w;
    ((bf16x8*)out)[i] = v;
}

// in f32 [R,C] -> out bf16 [C,R]
__global__ __launch_bounds__(256)
void transpose_cast_kernel(const float* __restrict__ in, __bf16* __restrict__ out,
                           int R, int C) {
    __shared__ float t[32][33];
    const int c0 = blockIdx.x * 32, r0 = blockIdx.y * 32;
    const int cc = threadIdx.x & 31, rr = threadIdx.x >> 5;   // rr 0..7
    #pragma unroll
    for (int i = 0; i < 32; i += 8)
        t[rr + i][cc] = in[(size_t)(r0 + rr + i) * C + c0 + cc];
    __syncthreads();
    #pragma unroll
    for (int i = 0; i < 32; i += 8)
        out[(size_t)(c0 + rr + i) * R + r0 + cc] = (__bf16)t[cc][rr + i];
}

// ---------------------------------------------------------------- softmaxes
__global__ __launch_bounds__(256)
void softmax4k_kernel(float* __restrict__ P) {
    float* p = P + (size_t)blockIdx.x * 4096;
    float v[16];
    float mx = -INFINITY;
    #pragma unroll
    for (int i = 0; i < 16; i++) {
        v[i] = p[threadIdx.x + i * 256];
        mx = fmaxf(mx, v[i]);
    }
    mx = blockReduceMax256(mx);
    float s = 0.f;
    #pragma unroll
    for (int i = 0; i < 16; i++) { v[i] = __expf(v[i] - mx); s += v[i]; }
    s = blockReduceSum256(s);
    const float inv = 1.f / s;
    #pragma unroll
    for (int i = 0; i < 16; i++) p[threadIdx.x + i * 256] = v[i] * inv;
}

__global__ __launch_bounds__(256)
void softmax_fc_kernel(float* __restrict__ P) {
    float* p = P + (size_t)blockIdx.x * 32000;
    float mx = -INFINITY;
    for (int i = threadIdx.x; i < 32000; i += 256) mx = fmaxf(mx, p[i]);
    mx = blockReduceMax256(mx);
    float s = 0.f;
    for (int i = threadIdx.x; i < 32000; i += 256) {
        float e = __expf(p[i] - mx);
        p[i] = e; s += e;
    }
    s = blockReduceSum256(s);
    const float inv = 1.f / s;
    for (int i = threadIdx.x; i < 32000; i += 256) p[i] *= inv;
}

// ---------------------------------------------------------------- assemble s (bf16)
__global__ __launch_bounds__(320)
void assemble_s_kernel(const int* __restrict__ X, const float* __restrict__ Emb,
                       const float* __restrict__ Cf, const float* __restrict__ Mo,
                       __bf16* __restrict__ S) {
    const int m = blockIdx.x;
    const int col = threadIdx.x * 4;
    float4 v;
    if (col < 256)      v = *(const float4*)(Emb + (size_t)X[m] * 256 + col);
    else if (col < 768) v = *(const float4*)(Cf + (size_t)m * 512 + (col - 256));
    else                v = *(const float4*)(Mo + (size_t)m * 512 + (col - 768));
    bf16x4 o;
    o[0] = (__bf16)v.x; o[1] = (__bf16)v.y; o[2] = (__bf16)v.z; o[3] = (__bf16)v.w;
    *(bf16x4*)(S + (size_t)m * 1280 + col) = o;
}

// ---------------------------------------------------------------- launch
extern "C" void kernel_launch(void* const* d_in, const int* in_sizes, int n_in,
                              void* d_out, int out_size, void* d_ws, size_t ws_size,
                              hipStream_t stream) {
    const int*   x    = (const int*)d_in[0];
    const int*   c    = (const int*)d_in[1];
    const float* emb  = (const float*)d_in[2];
    const float* w1 = (const float*)d_in[3],  *b1 = (const float*)d_in[4];
    const float* g1 = (const float*)d_in[5],  *be1 = (const float*)d_in[6];
    const float* w2 = (const float*)d_in[7],  *b2 = (const float*)d_in[8];
    const float* g2 = (const float*)d_in[9],  *be2 = (const float*)d_in[10];
    const float* w3 = (const float*)d_in[11], *b3 = (const float*)d_in[12];
    const float* g3 = (const float*)d_in[13], *be3 = (const float*)d_in[14];
    const float* w4 = (const float*)d_in[15], *b4 = (const float*)d_in[16];
    const float* g4 = (const float*)d_in[17], *be4 = (const float*)d_in[18];
    const float* w5 = (const float*)d_in[19], *b5 = (const float*)d_in[20];
    const float* g5 = (const float*)d_in[21], *be5 = (const float*)d_in[22];
    const float* fcW = (const float*)d_in[23], *fcb = (const float*)d_in[24];
    const float* memK = (const float*)d_in[25], *memV = (const float*)d_in[26];
    float* out = (float*)d_out;

    float* ws = (float*)d_ws;
    float* y1     = ws;                       // 1024*32*127 = 4,161,536 f
    float* y2     = ws + 4161536;             // 1024*64*62  = 3,964,928 f
    float* y3     = y1;                       // aliases
    float* y4     = y2;
    float* cfeat  = ws + 8126464;             // 1024*512
    float* scores = ws + 8650752;             // 1024*4096
    float* m_out  = ws + 12845056;            // 1024*512
    // bf16 region starts at float offset 13,369,344 (byte 53,477,376; 16B aligned)
    __bf16* bws      = (__bf16*)(ws + 13369344);
    __bf16* s_bf     = bws;                   // 1,310,720
    __bf16* y4_bf    = bws + 1310720;         // 3,670,016
    __bf16* cfeat_bf = bws + 4980736;         // 524,288
    __bf16* attn_bf  = bws + 5505024;         // 4,194,304
    __bf16* w5_bf    = bws + 9699328;         // 1,835,008
    __bf16* memK_bf  = bws + 11534336;        // 2,097,152
    __bf16* memVT_bf = bws + 13631488;        // 2,097,152
    __bf16* fcWT_bf  = bws + 15728640;        // 40,960,000  (total ~167 MB)

    // weight conversions (independent of activations)
    transpose_cast_kernel<<<dim3(1000, 40), 256, 0, stream>>>(fcW, fcWT_bf, 1280, 32000);
    transpose_cast_kernel<<<dim3(16, 128), 256, 0, stream>>>(memV, memVT_bf, 4096, 512);
    cast_bf16_kernel<<<1024, 256, 0, stream>>>(memK, memK_bf, 262144);
    cast_bf16_kernel<<<896, 256, 0, stream>>>(w5, w5_bf, 229376);

    // conv stack
    conv_lds_kernel<64, 8, 2, 2, 256, 127, 32, 32, 16, 16, true>
        <<<dim3(1, N_SAMP), 256, 0, stream>>>(nullptr, c, emb, w1, b1, y1);
    bn_kernel<<<32, 256, 0, stream>>>(y1, g1, be1, 32, 127, N_SAMP);
    conv_lds_kernel<32, 8, 2, 2, 127, 62, 64, 32, 8, 16, false>
        <<<dim3(2, N_SAMP), 256, 0, stream>>>(y1, nullptr, nullptr, w2, b2, y2);
    bn_kernel<<<64, 256, 0, stream>>>(y2, g2, be2, 64, 62, N_SAMP);
    conv_lds_kernel<64, 8, 2, 2, 62, 30, 128, 64, 8, 16, false>
        <<<dim3(2, N_SAMP), 256, 0, stream>>>(y2, nullptr, nullptr, w3, b3, y3);
    bn_kernel<<<128, 256, 0, stream>>>(y3, g3, be3, 128, 30, N_SAMP);
    conv_lds_kernel<128, 8, 2, 2, 30, 14, 256, 128, 8, 8, false>
        <<<dim3(2, N_SAMP), 256, 0, stream>>>(y3, nullptr, nullptr, w4, b4, y4);
    bn_kernel<<<256, 256, 0, stream>>>(y4, g4, be4, 256, 14, N_SAMP);

    // conv5 as MFMA GEMM: [1024,3584] x w5[512,3584]^T + b5, leaky
    cast_bf16_kernel<<<1792, 256, 0, stream>>>(y4, y4_bf, 458752);
    mfma_gemm_bt<<<dim3(8, 4), 256, 0, stream>>>(y4_bf, w5_bf, b5, cfeat,
                                                 1024, 512, 3584, 1.0f, 1);
    bn_kernel<<<512, 256, 0, stream>>>(cfeat, g5, be5, 512, 1, N_SAMP);

    // attention over memory
    cast_bf16_kernel<<<256, 256, 0, stream>>>(cfeat, cfeat_bf, 65536);
    mfma_gemm_bt<<<dim3(8, 32), 256, 0, stream>>>(cfeat_bf, memK_bf, nullptr, scores,
                                                  1024, 4096, 512, 0.04419417382415922f, 0);
    softmax4k_kernel<<<1024, 256, 0, stream>>>(scores);
    cast_bf16_kernel<<<2048, 256, 0, stream>>>(scores, attn_bf, 524288);
    mfma_gemm_bt<<<dim3(8, 4), 256, 0, stream>>>(attn_bf, memVT_bf, nullptr, m_out,
                                                 1024, 512, 4096, 1.0f, 0);

    // concat + fc + softmax
    assemble_s_kernel<<<1024, 320, 0, stream>>>(x, emb, cfeat, m_out, s_bf);
    mfma_gemm_bt<<<dim3(8, 250), 256, 0, stream>>>(s_bf, fcWT_bf, fcb, out,
                                                   1024, 32000, 1280, 1.0f, 0);
    softmax_fc_kernel<<<1024, 256, 0, stream>>>(out);
}